// Round 10
// baseline (66.272 us; speedup 1.0000x reference)
//
#include <hip/hip_runtime.h>

// Gated CRF 3D->2D loss, round 15: DECOMPOSITION PROBE #2 (triple reduce).
// Residual algebra: 61.6 = fill(41) + ~2 (boundaries/tiny restores) +
// {crf_cold + reduce} = 18.6us, with T_crf(warm)=6.0 measured (r12).
// Two consistent worlds: A) crf_cold~16 (post-fill L2-drain tax on the
// first kernel, structural) + reduce~2.5;  B) crf_cold~6.5 + reduce~12
// (1-block tail stalls on cross-XCD boundary). reduce_partials is
// idempotent -> launching it 3x is bitwise-identical and
// dur = base + 2*T_reduce discriminates: A -> ~67us, B -> ~86us.
// Kernel bodies unchanged from round 14 (best: 61.6us).

constexpr int N = 2, H = 64, W = 64, D = 64, R = 3;
constexpr int WD  = W * D;
constexpr int HWD = H * W * D;
constexpr float INV_SXY  = 1.0f / 6.0f;
constexpr float LOG2E    = 1.4426950408889634f;
constexpr float C2       = 50.0f * LOG2E;   // 0.5*(1/0.1)^2 * log2(e)
constexpr int NBLOCKS = 2 * 64 * 8;         // n x h x dq = 1024

__device__ __forceinline__ float exp2_fast(float x) {
    return __builtin_amdgcn_exp2f(x);       // v_exp_f32
}

// One offset group: 6 pairs, LDS-sourced, float2 per site.
// Tile layout: sT/yT[di][w][dd] = [4][64][8] floats, di = row offset 0..3.
template <int DI0, int DJ0, int DI1, int DJ1, int DI2, int DJ2,
          int DI3, int DJ3, int DI4, int DJ4, int DI5, int DJ5>
__device__ __forceinline__ float group_sum_lds(
    const float* __restrict__ sT, const float* __restrict__ yT,
    int w, int doff, int h, const float scv[2], const float bv[2]) {
    constexpr int DI[6] = {DI0, DI1, DI2, DI3, DI4, DI5};
    constexpr int DJ[6] = {DJ0, DJ1, DJ2, DJ3, DJ4, DJ5};

    bool   vld[6];
    float2 sn[6], an[6];

    #pragma unroll
    for (int p = 0; p < 6; ++p) {
        vld[p] = (h + DI[p] < H) &
                 ((unsigned)(w + DJ[p]) < (unsigned)W);
        const int wcl = min(max(w + DJ[p], 0), W - 1);
        const int off = (DI[p] * W + wcl) * 8 + doff;
        sn[p] = *(const float2*)(sT + off);
        an[p] = *(const float2*)(yT + off);
    }

    float acc0 = 0.0f, acc1 = 0.0f;
    #pragma unroll
    for (int p = 0; p < 6; ++p) {
        constexpr float d2[6] = {
            (float)(DI0 * DI0 + DJ0 * DJ0), (float)(DI1 * DI1 + DJ1 * DJ1),
            (float)(DI2 * DI2 + DJ2 * DJ2), (float)(DI3 * DI3 + DJ3 * DJ3),
            (float)(DI4 * DI4 + DJ4 * DJ4), (float)(DI5 * DI5 + DJ5 * DJ5)};
        const float A2  = -0.5f * d2[p] * (INV_SXY * INV_SXY) * LOG2E;
        const float A2e = vld[p] ? A2 : -1e30f;
        {
            const float dsr = sn[p].x - scv[0];
            const float k   = exp2_fast(__builtin_fmaf(-C2 * dsr, dsr, A2e));
            acc0 += k * (an[p].x + bv[0] - 2.0f * an[p].x * bv[0]);
        }
        {
            const float dsr = sn[p].y - scv[1];
            const float k   = exp2_fast(__builtin_fmaf(-C2 * dsr, dsr, A2e));
            acc1 += k * (an[p].y + bv[1] - 2.0f * an[p].y * bv[1]);
        }
    }
    return acc0 + acc1;
}

__global__ __launch_bounds__(256, 4) void crf_partial(
    const float* __restrict__ y,   // (N,2,H,W,D) -- only channel 0 read
    const float* __restrict__ s,   // (N,1,H,W,D)
    float* __restrict__ partial) {
    const int tid = threadIdx.x;
    const int bid = blockIdx.x;

    // XCD-slab remap: xcd (= bid&7, dispatch round-robin) owns h-slab
    // [8*xcd, 8*xcd+8), all dq and both n -> staging stays L2-local.
    const int xcd = bid & 7;
    const int q   = bid >> 3;             // 0..127
    const int h   = (xcd << 3) | (q & 7);
    const int dq  = (q >> 3) & 7;         // d-eighth 0..7
    const int n   = q >> 6;
    const int pidx = (((n << 6) + h) << 3) | dq;  // canonical partial index
    const int d0b  = dq << 3;             // base d of this 8-float chunk

    const float* sb  = s + (size_t)n * HWD;
    const float* y0b = y + (size_t)n * (2 * HWD);

    // --- Stage tile rows h..h+3 (clamped), full W, 8 d-floats -----------
    __shared__ float sT[4 * 64 * 8];      // 8 KB
    __shared__ float yT[4 * 64 * 8];      // 8 KB
    #pragma unroll
    for (int k = 0; k < 2; ++k) {
        const int f4   = tid + (k << 8);           // 0..511 float4 index
        const int fidx = f4 << 2;                  // float index in tile
        const int c    = fidx >> 9;                // row 0..3
        const int wg   = (fidx >> 3) & 63;
        const int dd   = fidx & 7;                 // 0 or 4
        const int hh   = min(h + c, H - 1);        // clamp; masked later
        const int gidx = hh * WD + wg * D + d0b + dd;
        *(float4*)(sT + fidx) = *(const float4*)(sb  + gidx);
        *(float4*)(yT + fidx) = *(const float4*)(y0b + gidx);
    }
    __syncthreads();
    // -------------------------------------------------------------------

    const int w    = tid >> 2;            // 0..63
    const int doff = (tid & 3) << 1;      // 0,2,4,6 (float offset in chunk)

    const float2 sc2 = *(const float2*)(sT + w * 8 + doff);
    const float2 b2  = *(const float2*)(yT + w * 8 + doff);
    const float scv[2] = {sc2.x, sc2.y};
    const float bv[2]  = {b2.x,  b2.y};

    // All 24 symmetric pair offsets (di>=0), in the round-6 group order.
    float acc = 0.0f;
    acc += group_sum_lds<0, 1, 0, 2, 0, 3, 1, -3, 1, -2, 1, -1>(
        sT, yT, w, doff, h, scv, bv);
    acc += group_sum_lds<1, 0, 1, 1, 1, 2, 1, 3, 2, -3, 2, -2>(
        sT, yT, w, doff, h, scv, bv);
    acc += group_sum_lds<2, -1, 2, 0, 2, 1, 2, 2, 2, 3, 3, -3>(
        sT, yT, w, doff, h, scv, bv);
    acc += group_sum_lds<3, -2, 3, -1, 3, 0, 3, 1, 3, 2, 3, 3>(
        sT, yT, w, doff, h, scv, bv);

    // OOB closed form (window truncation), once per (h,w,d) site.
    float extra = 0.0f;
    {
        const int nrows = min(h + R, H - 1) - max(h - R, 0) + 1;
        const int ncols = min(w + R, W - 1) - max(w - R, 0) + 1;
        const int oob = 49 - nrows * ncols;
        if (oob) {
            const float fh = (float)h * INV_SXY;
            const float fw = (float)w * INV_SXY;
            const float base2 = -0.5f * (fh * fh + fw * fw) * LOG2E;
            float koob = 0.0f;
            #pragma unroll
            for (int j = 0; j < 2; ++j)
                koob += exp2_fast(__builtin_fmaf(-C2 * scv[j], scv[j], base2));
            extra = (float)oob * koob;
        }
    }

    float part = 2.0f * acc + extra;

    #pragma unroll
    for (int off = 32; off; off >>= 1)
        part += __shfl_down(part, off, 64);

    __shared__ float wsum[4];
    if ((tid & 63) == 0) wsum[tid >> 6] = part;
    __syncthreads();
    if (tid == 0) partial[pidx] = wsum[0] + wsum[1] + wsum[2] + wsum[3];
}

__global__ __launch_bounds__(256) void reduce_partials(
    const float* __restrict__ partial, float* __restrict__ out) {
    const int tid = threadIdx.x;
    float v = 0.0f;
    #pragma unroll
    for (int i = 0; i < NBLOCKS / 256; ++i)
        v += partial[tid + i * 256];
    #pragma unroll
    for (int off = 32; off; off >>= 1)
        v += __shfl_down(v, off, 64);
    __shared__ float wsum[4];
    if ((tid & 63) == 0) wsum[tid >> 6] = v;
    __syncthreads();
    if (tid == 0)
        out[0] = (wsum[0] + wsum[1] + wsum[2] + wsum[3]) *
                 (1.0f / (float)(N * D * H * W));
}

extern "C" void kernel_launch(void* const* d_in, const int* in_sizes, int n_in,
                              void* d_out, int out_size, void* d_ws, size_t ws_size,
                              hipStream_t stream) {
    const float* y = (const float*)d_in[0];
    const float* s = (const float*)d_in[1];
    float* partial = (float*)d_ws;   // NBLOCKS floats, all written before read

    crf_partial<<<dim3(NBLOCKS), dim3(256), 0, stream>>>(y, s, partial);
    // PROBE: three identical idempotent reduce dispatches.
    // dur_us = base + 2*T_reduce.
    reduce_partials<<<dim3(1), dim3(256), 0, stream>>>(partial, (float*)d_out);
    reduce_partials<<<dim3(1), dim3(256), 0, stream>>>(partial, (float*)d_out);
    reduce_partials<<<dim3(1), dim3(256), 0, stream>>>(partial, (float*)d_out);
}

// Round 11
// 61.186 us; speedup vs baseline: 1.0831x; 1.0831x over previous
//
#include <hip/hip_runtime.h>

// Gated CRF 3D->2D loss, FINAL (round 14 restored): LDS-staged interior,
// occupancy 4 blocks/CU, two-kernel structure. 61.6us measured.
//
// Closed budget (all measured): fill 41.0 (harness, 83% HBM peak)
// + post-fill L2-drain tax ~10 (migrates to first kernel; r10/r12)
// + crf warm ~5.5 (r12 probe) + reduce 2.3 (r15 probe) + boundaries ~2.
// Structural floor ~51us is harness-fixed. Coordination ledger: agent
// RMW ~25ns/op serialized (r8: 2048 ops ~50us, r13: 512 ops ~13us) ->
// the 1-block reduce dispatch is the cheapest grid-wide sync; keep it.

constexpr int N = 2, H = 64, W = 64, D = 64, R = 3;
constexpr int WD  = W * D;
constexpr int HWD = H * W * D;
constexpr float INV_SXY  = 1.0f / 6.0f;
constexpr float LOG2E    = 1.4426950408889634f;
constexpr float C2       = 50.0f * LOG2E;   // 0.5*(1/0.1)^2 * log2(e)
constexpr int NBLOCKS = 2 * 64 * 8;         // n x h x dq = 1024

__device__ __forceinline__ float exp2_fast(float x) {
    return __builtin_amdgcn_exp2f(x);       // v_exp_f32
}

// One offset group: 6 pairs, LDS-sourced, float2 per site.
// Tile layout: sT/yT[di][w][dd] = [4][64][8] floats, di = row offset 0..3.
template <int DI0, int DJ0, int DI1, int DJ1, int DI2, int DJ2,
          int DI3, int DJ3, int DI4, int DJ4, int DI5, int DJ5>
__device__ __forceinline__ float group_sum_lds(
    const float* __restrict__ sT, const float* __restrict__ yT,
    int w, int doff, int h, const float scv[2], const float bv[2]) {
    constexpr int DI[6] = {DI0, DI1, DI2, DI3, DI4, DI5};
    constexpr int DJ[6] = {DJ0, DJ1, DJ2, DJ3, DJ4, DJ5};

    bool   vld[6];
    float2 sn[6], an[6];

    // Phase 1: all 12 ds_read_b64 batched (wave spans 512 contiguous B:
    // conflict-free).
    #pragma unroll
    for (int p = 0; p < 6; ++p) {
        vld[p] = (h + DI[p] < H) &
                 ((unsigned)(w + DJ[p]) < (unsigned)W);
        const int wcl = min(max(w + DJ[p], 0), W - 1);
        const int off = (DI[p] * W + wcl) * 8 + doff;
        sn[p] = *(const float2*)(sT + off);
        an[p] = *(const float2*)(yT + off);
    }

    // Phase 2: compute. Invalid pairs get A2 = -1e30 -> exp2 -> 0.
    float acc0 = 0.0f, acc1 = 0.0f;
    #pragma unroll
    for (int p = 0; p < 6; ++p) {
        constexpr float d2[6] = {
            (float)(DI0 * DI0 + DJ0 * DJ0), (float)(DI1 * DI1 + DJ1 * DJ1),
            (float)(DI2 * DI2 + DJ2 * DJ2), (float)(DI3 * DI3 + DJ3 * DJ3),
            (float)(DI4 * DI4 + DJ4 * DJ4), (float)(DI5 * DI5 + DJ5 * DJ5)};
        const float A2  = -0.5f * d2[p] * (INV_SXY * INV_SXY) * LOG2E;
        const float A2e = vld[p] ? A2 : -1e30f;
        {
            const float dsr = sn[p].x - scv[0];
            const float k   = exp2_fast(__builtin_fmaf(-C2 * dsr, dsr, A2e));
            acc0 += k * (an[p].x + bv[0] - 2.0f * an[p].x * bv[0]);
        }
        {
            const float dsr = sn[p].y - scv[1];
            const float k   = exp2_fast(__builtin_fmaf(-C2 * dsr, dsr, A2e));
            acc1 += k * (an[p].y + bv[1] - 2.0f * an[p].y * bv[1]);
        }
    }
    return acc0 + acc1;
}

__global__ __launch_bounds__(256, 4) void crf_partial(
    const float* __restrict__ y,   // (N,2,H,W,D) -- only channel 0 read
    const float* __restrict__ s,   // (N,1,H,W,D)
    float* __restrict__ partial) {
    const int tid = threadIdx.x;
    const int bid = blockIdx.x;

    // XCD-slab remap: xcd (= bid&7, dispatch round-robin) owns h-slab
    // [8*xcd, 8*xcd+8), all dq and both n -> staging stays L2-local.
    const int xcd = bid & 7;
    const int q   = bid >> 3;             // 0..127
    const int h   = (xcd << 3) | (q & 7);
    const int dq  = (q >> 3) & 7;         // d-eighth 0..7
    const int n   = q >> 6;
    const int pidx = (((n << 6) + h) << 3) | dq;  // canonical partial index
    const int d0b  = dq << 3;             // base d of this 8-float chunk

    const float* sb  = s + (size_t)n * HWD;
    const float* y0b = y + (size_t)n * (2 * HWD);

    // --- Stage tile rows h..h+3 (clamped), full W, 8 d-floats -----------
    __shared__ float sT[4 * 64 * 8];      // 8 KB
    __shared__ float yT[4 * 64 * 8];      // 8 KB
    #pragma unroll
    for (int k = 0; k < 2; ++k) {
        const int f4   = tid + (k << 8);           // 0..511 float4 index
        const int fidx = f4 << 2;                  // float index in tile
        const int c    = fidx >> 9;                // row 0..3
        const int wg   = (fidx >> 3) & 63;
        const int dd   = fidx & 7;                 // 0 or 4
        const int hh   = min(h + c, H - 1);        // clamp; masked later
        const int gidx = hh * WD + wg * D + d0b + dd;
        *(float4*)(sT + fidx) = *(const float4*)(sb  + gidx);
        *(float4*)(yT + fidx) = *(const float4*)(y0b + gidx);
    }
    __syncthreads();
    // -------------------------------------------------------------------

    const int w    = tid >> 2;            // 0..63
    const int doff = (tid & 3) << 1;      // 0,2,4,6 (float offset in chunk)

    const float2 sc2 = *(const float2*)(sT + w * 8 + doff);
    const float2 b2  = *(const float2*)(yT + w * 8 + doff);
    const float scv[2] = {sc2.x, sc2.y};
    const float bv[2]  = {b2.x,  b2.y};

    // All 24 symmetric pair offsets (di>=0), in the round-6 group order.
    float acc = 0.0f;
    acc += group_sum_lds<0, 1, 0, 2, 0, 3, 1, -3, 1, -2, 1, -1>(
        sT, yT, w, doff, h, scv, bv);
    acc += group_sum_lds<1, 0, 1, 1, 1, 2, 1, 3, 2, -3, 2, -2>(
        sT, yT, w, doff, h, scv, bv);
    acc += group_sum_lds<2, -1, 2, 0, 2, 1, 2, 2, 2, 3, 3, -3>(
        sT, yT, w, doff, h, scv, bv);
    acc += group_sum_lds<3, -2, 3, -1, 3, 0, 3, 1, 3, 2, 3, 3>(
        sT, yT, w, doff, h, scv, bv);

    // OOB closed form (window truncation), once per (h,w,d) site.
    float extra = 0.0f;
    {
        const int nrows = min(h + R, H - 1) - max(h - R, 0) + 1;
        const int ncols = min(w + R, W - 1) - max(w - R, 0) + 1;
        const int oob = 49 - nrows * ncols;
        if (oob) {
            const float fh = (float)h * INV_SXY;
            const float fw = (float)w * INV_SXY;
            const float base2 = -0.5f * (fh * fh + fw * fw) * LOG2E;
            float koob = 0.0f;
            #pragma unroll
            for (int j = 0; j < 2; ++j)
                koob += exp2_fast(__builtin_fmaf(-C2 * scv[j], scv[j], base2));
            extra = (float)oob * koob;
        }
    }

    float part = 2.0f * acc + extra;

    #pragma unroll
    for (int off = 32; off; off >>= 1)
        part += __shfl_down(part, off, 64);

    __shared__ float wsum[4];
    if ((tid & 63) == 0) wsum[tid >> 6] = part;
    __syncthreads();
    if (tid == 0) partial[pidx] = wsum[0] + wsum[1] + wsum[2] + wsum[3];
}

__global__ __launch_bounds__(256) void reduce_partials(
    const float* __restrict__ partial, float* __restrict__ out) {
    const int tid = threadIdx.x;
    float v = 0.0f;
    #pragma unroll
    for (int i = 0; i < NBLOCKS / 256; ++i)
        v += partial[tid + i * 256];
    #pragma unroll
    for (int off = 32; off; off >>= 1)
        v += __shfl_down(v, off, 64);
    __shared__ float wsum[4];
    if ((tid & 63) == 0) wsum[tid >> 6] = v;
    __syncthreads();
    if (tid == 0)
        out[0] = (wsum[0] + wsum[1] + wsum[2] + wsum[3]) *
                 (1.0f / (float)(N * D * H * W));
}

extern "C" void kernel_launch(void* const* d_in, const int* in_sizes, int n_in,
                              void* d_out, int out_size, void* d_ws, size_t ws_size,
                              hipStream_t stream) {
    const float* y = (const float*)d_in[0];
    const float* s = (const float*)d_in[1];
    float* partial = (float*)d_ws;   // NBLOCKS floats, all written before read

    crf_partial<<<dim3(NBLOCKS), dim3(256), 0, stream>>>(y, s, partial);
    reduce_partials<<<dim3(1), dim3(256), 0, stream>>>(partial, (float*)d_out);
}